// Round 1
// baseline (2543.037 us; speedup 1.0000x reference)
//
#include <hip/hip_runtime.h>
#include <math.h>

#define BATCH 2
#define SEQ   2048
#define EMB   1024
#define NHEAD 16
#define DHEAD 64

// ---------------- positional encoding table ----------------
__global__ void pos_init(float* __restrict__ pos) {
    int s = blockIdx.x;
    int d = threadIdx.x;              // 0..63
    int i = d >> 1;
    float expo  = (float)(2 * i) / (float)DHEAD;
    float scale = 1.0f / (powf(10000.0f, expo) + 1.1920928955078125e-07f);
    float ang   = (float)s * scale;
    pos[s * DHEAD + d] = (d & 1) ? cosf(ang) : sinf(ang);
}

// ---------------- fp32 tiled GEMM: C[M,N] = A[M,K] @ B[K,N] (+pos) ----------
#define BM 64
#define BN 64
#define BK 16

__global__ __launch_bounds__(256) void gemm_f32(
    const float* __restrict__ A, const float* __restrict__ B,
    float* __restrict__ C, const float* __restrict__ pos, int addpos,
    int M, int N, int K) {
    __shared__ float As[BK][BM];   // transposed: As[k][m]
    __shared__ float Bs[BK][BN];   // Bs[k][n]

    const int tid = threadIdx.x;
    const int bm  = blockIdx.x * BM;
    const int bn  = blockIdx.y * BN;
    const int tx  = tid & 15;          // n-group 0..15
    const int ty  = tid >> 4;          // m-group 0..15
    const int arow = tid >> 2;         // 0..63
    const int acol = (tid & 3) << 2;   // 0,4,8,12
    const int brow = tid >> 4;         // 0..15
    const int bcol = (tid & 15) << 2;  // 0..60

    float acc[4][4] = {{0.f}};

    const float* Aptr = A + (size_t)(bm + arow) * K + acol;
    const float* Bptr = B + (size_t)brow * N + bn + bcol;

    for (int k0 = 0; k0 < K; k0 += BK) {
        float4 av = *(const float4*)(Aptr + k0);
        float4 bv = *(const float4*)(Bptr + (size_t)k0 * N);
        __syncthreads();
        As[acol + 0][arow] = av.x;
        As[acol + 1][arow] = av.y;
        As[acol + 2][arow] = av.z;
        As[acol + 3][arow] = av.w;
        *(float4*)&Bs[brow][bcol] = bv;
        __syncthreads();
#pragma unroll
        for (int kk = 0; kk < BK; ++kk) {
            float4 a = *(const float4*)&As[kk][ty << 2];
            float4 b = *(const float4*)&Bs[kk][tx << 2];
            float aa[4] = {a.x, a.y, a.z, a.w};
            float bb[4] = {b.x, b.y, b.z, b.w};
#pragma unroll
            for (int i = 0; i < 4; ++i)
#pragma unroll
                for (int j = 0; j < 4; ++j)
                    acc[i][j] += aa[i] * bb[j];
        }
    }

#pragma unroll
    for (int i = 0; i < 4; ++i) {
        int m = bm + (ty << 2) + i;
        int n = bn + (tx << 2);
        float4 v = make_float4(acc[i][0], acc[i][1], acc[i][2], acc[i][3]);
        if (addpos) {
            int s = m & (SEQ - 1);
            int d = n & (DHEAD - 1);   // multiple of 4
            float4 p = *(const float4*)&pos[s * DHEAD + d];
            v.x += p.x; v.y += p.y; v.z += p.z; v.w += p.w;
        }
        *(float4*)&C[(size_t)m * N + n] = v;
    }
}

// ---------------- flash-style causal attention, 1 thread = 1 q-row ---------
#define QT 128
#define KT 32

__global__ __launch_bounds__(QT) void attn_fwd(
    const float* __restrict__ Q, const float* __restrict__ Kg,
    const float* __restrict__ V, float* __restrict__ O) {
    __shared__ float Ks[KT][DHEAD];
    __shared__ float Vs[KT][DHEAD];

    const int t    = threadIdx.x;
    const int q0   = blockIdx.x * QT;
    const int bh   = blockIdx.y;
    const int b    = bh >> 4;
    const int h    = bh & 15;
    const int qrow = q0 + t;
    const size_t base = (size_t)b * SEQ * EMB + (size_t)h * DHEAD;

    float4 q4[16], o4[16];
#pragma unroll
    for (int i = 0; i < 16; ++i) {
        q4[i] = *(const float4*)&Q[base + (size_t)qrow * EMB + i * 4];
        o4[i] = make_float4(0.f, 0.f, 0.f, 0.f);
    }
    float m_i = -3.0e38f, l_i = 0.0f;
    const float scale = 0.03125f;  // 1024^-0.5

    const int kend = q0 + QT;      // causal: keys < kend
    for (int k0 = 0; k0 < kend; k0 += KT) {
        __syncthreads();
#pragma unroll
        for (int i = 0; i < 4; ++i) {
            int idx = t + i * QT;            // 0..511
            int r = idx >> 4;
            int c = (idx & 15) << 2;
            *(float4*)&Ks[r][c] = *(const float4*)&Kg[base + (size_t)(k0 + r) * EMB + c];
            *(float4*)&Vs[r][c] = *(const float4*)&V [base + (size_t)(k0 + r) * EMB + c];
        }
        __syncthreads();

        float sv[KT];
        float mt = m_i;
#pragma unroll
        for (int j = 0; j < KT; ++j) {
            const float4* kr = (const float4*)Ks[j];
            float dot = 0.f;
#pragma unroll
            for (int dd = 0; dd < 16; ++dd) {
                float4 kv = kr[dd];
                dot += q4[dd].x * kv.x + q4[dd].y * kv.y +
                       q4[dd].z * kv.z + q4[dd].w * kv.w;
            }
            sv[j] = (k0 + j <= qrow) ? dot * scale : -3.0e38f;
            mt = fmaxf(mt, sv[j]);
        }

        float corr = __expf(m_i - mt);
        l_i *= corr;
#pragma unroll
        for (int i = 0; i < 16; ++i) {
            o4[i].x *= corr; o4[i].y *= corr; o4[i].z *= corr; o4[i].w *= corr;
        }
#pragma unroll
        for (int j = 0; j < KT; ++j) {
            float p = __expf(sv[j] - mt);
            l_i += p;
            const float4* vr = (const float4*)Vs[j];
#pragma unroll
            for (int dd = 0; dd < 16; ++dd) {
                float4 vv = vr[dd];
                o4[dd].x += p * vv.x; o4[dd].y += p * vv.y;
                o4[dd].z += p * vv.z; o4[dd].w += p * vv.w;
            }
        }
        m_i = mt;
    }

    float inv = 1.0f / l_i;
#pragma unroll
    for (int i = 0; i < 16; ++i) {
        float4 v = o4[i];
        v.x *= inv; v.y *= inv; v.z *= inv; v.w *= inv;
        *(float4*)&O[base + (size_t)qrow * EMB + i * 4] = v;
    }
}

// ---------------- launch ----------------
extern "C" void kernel_launch(void* const* d_in, const int* in_sizes, int n_in,
                              void* d_out, int out_size, void* d_ws, size_t ws_size,
                              hipStream_t stream) {
    const float* x  = (const float*)d_in[0];
    const float* Wq = (const float*)d_in[1];
    const float* Wk = (const float*)d_in[2];
    const float* Wv = (const float*)d_in[3];
    const float* Wo = (const float*)d_in[4];
    float* out = (float*)d_out;

    float* ws  = (float*)d_ws;
    float* pos = ws;                          // S*64            = 131072 floats
    float* Qb  = pos + SEQ * DHEAD;           // B*S*E           = 4194304
    float* Kb  = Qb + (size_t)BATCH * SEQ * EMB;
    float* Vb  = Kb + (size_t)BATCH * SEQ * EMB;
    float* AO  = Vb + (size_t)BATCH * SEQ * EMB;

    const int M = BATCH * SEQ, N = EMB, K = EMB;

    pos_init<<<SEQ, DHEAD, 0, stream>>>(pos);

    dim3 g(M / BM, N / BN), blk(256);
    gemm_f32<<<g, blk, 0, stream>>>(x,  Wq, Qb, pos, 1, M, N, K);
    gemm_f32<<<g, blk, 0, stream>>>(x,  Wk, Kb, pos, 1, M, N, K);
    gemm_f32<<<g, blk, 0, stream>>>(x,  Wv, Vb, pos, 0, M, N, K);

    attn_fwd<<<dim3(SEQ / QT, BATCH * NHEAD), QT, 0, stream>>>(Qb, Kb, Vb, AO);

    gemm_f32<<<g, blk, 0, stream>>>(AO, Wo, out, pos, 0, M, N, K);
}